// Round 3
// baseline (233.233 us; speedup 1.0000x reference)
//
#include <hip/hip_runtime.h>
#include <hip/hip_bf16.h>
#include <math.h>

#define N_TOTAL 8192
#define D_DIM   256
#define INV_T   10.0f
#define BM 128
#define BN 128
#define BK 32
#define NT 64          // 8192/128; triangular grid = NT*(NT+1)/2 = 2080
#define NBLOCKS (NT * (NT + 1) / 2)

typedef __bf16 bf16_8 __attribute__((ext_vector_type(8)));
typedef float  f32x4  __attribute__((ext_vector_type(4)));

typedef const __attribute__((address_space(1))) unsigned int* gptr_t;
typedef __attribute__((address_space(3))) unsigned int*       lptr_t;

// async global->LDS, 16B/lane; LDS dest = wave-uniform base + lane*16 [m97/m104]
__device__ __forceinline__ void gload16(const void* g, void* l) {
    __builtin_amdgcn_global_load_lds((gptr_t)g, (lptr_t)l, 16, 0, 0);
}

__device__ __forceinline__ unsigned short f2bf(float f) {
    unsigned int u = __float_as_uint(f);
    return (unsigned short)((u + 0x7FFFu + ((u >> 16) & 1u)) >> 16);
}

// Kernel 1: L2-normalize concat(q,k) -> bf16 F[8192][256]; zero S and counter.
__global__ __launch_bounds__(256) void normalize_kernel(
    const float* __restrict__ q, const float* __restrict__ k,
    unsigned short* __restrict__ F, float* __restrict__ S, int* __restrict__ counter)
{
    if (threadIdx.x < 4) S[blockIdx.x * 4 + threadIdx.x] = 0.f;
    if (blockIdx.x == 0 && threadIdx.x == 0) *counter = 0;
    int row  = blockIdx.x * 4 + (threadIdx.x >> 6);
    int lane = threadIdx.x & 63;
    const float* src = (row < 4096) ? (q + (size_t)row * D_DIM)
                                    : (k + (size_t)(row - 4096) * D_DIM);
    float4 v = ((const float4*)src)[lane];
    float ss = v.x*v.x + v.y*v.y + v.z*v.z + v.w*v.w;
    #pragma unroll
    for (int off = 32; off > 0; off >>= 1) ss += __shfl_xor(ss, off, 64);
    float inv = 1.0f / fmaxf(sqrtf(ss), 1e-12f);
    ushort4 o;
    o.x = f2bf(v.x * inv); o.y = f2bf(v.y * inv);
    o.z = f2bf(v.z * inv); o.w = f2bf(v.w * inv);
    ((ushort4*)(F + (size_t)row * D_DIM))[lane] = o;
}

__device__ __forceinline__ int tri_off(int x) { return x * NT - (x * (x - 1)) / 2; }

// Kernel 2: upper-triangular tiled F*F^T, fused exp epilogue + last-block finalize.
__global__ __launch_bounds__(256) void simloss_gemm(
    const __hip_bfloat16* __restrict__ F,
    float* __restrict__ S, float* __restrict__ pos,
    int* __restrict__ counter, float* __restrict__ out)
{
    // LDS: [row][4 chunks of 8 bf16], chunk slot rotated by (row>>2)&3. 8 KB each.
    __shared__ __hip_bfloat16 As[BM * BK];
    __shared__ __hip_bfloat16 Bs[BN * BK];
    __shared__ float fsum[4];

    // invert linear block id -> (bx, by), bx <= by
    int b  = blockIdx.x;
    int bx = (int)(64.5f - sqrtf(64.5f * 64.5f - 2.0f * (float)b));
    if (bx < 0) bx = 0; if (bx > NT - 1) bx = NT - 1;
    while (bx > 0 && tri_off(bx) > b) --bx;
    while (bx < NT - 1 && tri_off(bx + 1) <= b) ++bx;
    const int by = bx + (b - tri_off(bx));
    const bool is_diag = (bx == by);

    const int i0 = bx * BM;
    const int j0 = by * BN;
    const int tid  = threadIdx.x;
    const int wave = tid >> 6;
    const int lane = tid & 63;
    const int wm = (wave & 1) * 64;
    const int wn = (wave >> 1) * 64;
    const int g  = lane >> 4;
    const int cj = lane & 15;

    // staging lane mapping: row-in-group = lane>>2, slot = lane&3,
    // global chunk = (slot - rot)&3 with rot = (row>>2)&3 = (lane>>4)&3
    const int s_r16 = lane >> 2;
    const int s_cg  = ((lane & 3) - (s_r16 >> 2)) & 3;

    // fragment LDS element offsets (loop-invariant): row*32 + slot*8,
    // slot = (g + (row>>2)&3)&3 to fetch global chunk g
    int a_off[4], b_off[4];
    #pragma unroll
    for (int t = 0; t < 4; ++t) {
        int ra = wm + t * 16 + cj;
        a_off[t] = ra * BK + (((g + (ra >> 2)) & 3) * 8);
        int rb = wn + t * 16 + cj;
        b_off[t] = rb * BK + (((g + (rb >> 2)) & 3) * 8);
    }

    f32x4 acc[4][4];
    #pragma unroll
    for (int a = 0; a < 4; ++a)
        #pragma unroll
        for (int c = 0; c < 4; ++c)
            acc[a][c] = (f32x4){0.f, 0.f, 0.f, 0.f};

    for (int kk = 0; kk < D_DIM; kk += BK) {
        // wave stages A rows [wave*32, +32) and B rows [wave*32, +32), 16 rows/instr
        #pragma unroll
        for (int p = 0; p < 2; ++p) {
            const int R0 = wave * 32 + p * 16;
            gload16(F + (size_t)(i0 + R0 + s_r16) * D_DIM + kk + s_cg * 8, &As[R0 * BK]);
            gload16(F + (size_t)(j0 + R0 + s_r16) * D_DIM + kk + s_cg * 8, &Bs[R0 * BK]);
        }
        __syncthreads();

        bf16_8 a[4], bfr[4];
        #pragma unroll
        for (int t = 0; t < 4; ++t) {
            a[t]   = *(const bf16_8*)(&As[a_off[t]]);
            bfr[t] = *(const bf16_8*)(&Bs[b_off[t]]);
        }
        #pragma unroll
        for (int ti = 0; ti < 4; ++ti)
            #pragma unroll
            for (int tj = 0; tj < 4; ++tj)
                acc[ti][tj] = __builtin_amdgcn_mfma_f32_16x16x32_bf16(
                    a[ti], bfr[tj], acc[ti][tj], 0, 0, 0);
        __syncthreads();
    }

    // ---- epilogue. C/D layout: col = lane&15, row = (lane>>4)*4 + reg [m89/m91]
    // positives: tiles by==bx+32, local diagonal, waves with wm==wn
    if (by == bx + 32 && wm == wn && (cj >> 2) == g) {
        #pragma unroll
        for (int ti = 0; ti < 4; ++ti) {
            float v = acc[ti][ti][cj & 3];
            int i = i0 + wm + ti * 16 + cj;
            pos[i] = v; pos[i + 4096] = v;
        }
    }
    // diag tiles: poison self-similarity elements so exp -> 0 (waves 1,2 have none)
    if (is_diag && wm == wn && (cj >> 2) == g) {
        #pragma unroll
        for (int ti = 0; ti < 4; ++ti) acc[ti][ti][cj & 3] = -1e30f;
    }

    float colsum[4] = {0.f, 0.f, 0.f, 0.f};
    #pragma unroll
    for (int ti = 0; ti < 4; ++ti) {
        #pragma unroll
        for (int r = 0; r < 4; ++r) {
            float es = 0.f;
            #pragma unroll
            for (int tj = 0; tj < 4; ++tj) {
                float e = __expf(acc[ti][tj][r] * INV_T);
                es += e;
                colsum[tj] += e;
            }
            #pragma unroll
            for (int off = 1; off < 16; off <<= 1)
                es += __shfl_xor(es, off, 64);
            if (cj == 0) atomicAdd(&S[i0 + wm + ti * 16 + g * 4 + r], es);
        }
    }
    if (!is_diag) {
        #pragma unroll
        for (int tj = 0; tj < 4; ++tj) {
            float cs = colsum[tj];
            cs += __shfl_xor(cs, 16, 64);
            cs += __shfl_xor(cs, 32, 64);
            if (g == 0) atomicAdd(&S[j0 + wn + tj * 16 + cj], cs);
        }
    }

    // ---- last block computes the loss
    __threadfence();
    __shared__ int is_last;
    if (tid == 0) is_last = (atomicAdd(counter, 1) == NBLOCKS - 1) ? 1 : 0;
    __syncthreads();
    if (is_last) {
        __threadfence();
        float acc2 = 0.f;
        for (int i = tid; i < N_TOTAL; i += 256)
            acc2 += __logf(S[i]) - pos[i] * INV_T;
        #pragma unroll
        for (int off = 32; off > 0; off >>= 1) acc2 += __shfl_xor(acc2, off, 64);
        if (lane == 0) fsum[wave] = acc2;
        __syncthreads();
        if (tid == 0)
            out[0] = (fsum[0] + fsum[1] + fsum[2] + fsum[3]) * (1.0f / N_TOTAL);
    }
}

extern "C" void kernel_launch(void* const* d_in, const int* in_sizes, int n_in,
                              void* d_out, int out_size, void* d_ws, size_t ws_size,
                              hipStream_t stream) {
    const float* q = (const float*)d_in[0];
    const float* k = (const float*)d_in[1];
    float* out = (float*)d_out;

    char* ws = (char*)d_ws;
    const size_t f_bytes = (size_t)N_TOTAL * D_DIM * sizeof(unsigned short); // 4 MB
    unsigned short* F = (unsigned short*)ws;
    float* S     = (float*)(ws + f_bytes);
    float* pos   = (float*)(ws + f_bytes + N_TOTAL * sizeof(float));
    int*   cnt   = (int*)(ws + f_bytes + 2 * N_TOTAL * sizeof(float));

    normalize_kernel<<<N_TOTAL / 4, 256, 0, stream>>>(q, k, F, S, cnt);
    simloss_gemm<<<NBLOCKS, 256, 0, stream>>>((const __hip_bfloat16*)F, S, pos, cnt, out);
}

// Round 4
// 135.459 us; speedup vs baseline: 1.7218x; 1.7218x over previous
//
#include <hip/hip_runtime.h>
#include <hip/hip_bf16.h>
#include <math.h>

#define N_TOTAL 8192
#define D_DIM   256
#define INV_T   10.0f
#define BM 128
#define BN 128
#define BK 32
#define NCHUNK (D_DIM / 8)     // 32 chunks of 8 bf16 (16 B) per row
#define NT 64                  // 8192/128; triangular grid
#define NBLOCKS (NT * (NT + 1) / 2)

typedef __bf16 bf16_8 __attribute__((ext_vector_type(8)));
typedef float  f32x4  __attribute__((ext_vector_type(4)));

typedef const __attribute__((address_space(1))) unsigned int* gptr_t;
typedef __attribute__((address_space(3))) unsigned int*       lptr_t;

// async global->LDS, 16B/lane; global addr per-lane, LDS dest = uniform base + lane*16
__device__ __forceinline__ void gload16(const void* g, void* l) {
    __builtin_amdgcn_global_load_lds((gptr_t)g, (lptr_t)l, 16, 0, 0);
}

__device__ __forceinline__ unsigned short f2bf(float f) {
    unsigned int u = __float_as_uint(f);
    return (unsigned short)((u + 0x7FFFu + ((u >> 16) & 1u)) >> 16);
}

// Kernel 1: L2-normalize concat(q,k) -> Fs in chunk-major layout:
// Fs[(c*8192 + row)*8 .. +8) = bf16 elements 8c..8c+7 of row. Also zero S/counter/possum.
// Half-wave (32 lanes) per row: lane = 32*h + c.
__global__ __launch_bounds__(256) void normalize_stage(
    const float* __restrict__ q, const float* __restrict__ k,
    unsigned short* __restrict__ Fs, float* __restrict__ S,
    int* __restrict__ counter, float* __restrict__ possum)
{
    const int tid = threadIdx.x;
    if (tid < 8) S[blockIdx.x * 8 + tid] = 0.f;
    if (blockIdx.x == 0 && tid == 0) { *counter = 0; *possum = 0.f; }

    const int wave = tid >> 6, lane = tid & 63;
    const int h = lane >> 5, c = lane & 31;
    const int row = blockIdx.x * 8 + wave * 2 + h;
    const float* src = (row < 4096) ? q + (size_t)row * D_DIM
                                    : k + (size_t)(row - 4096) * D_DIM;
    float4 v0 = *(const float4*)(src + c * 8);
    float4 v1 = *(const float4*)(src + c * 8 + 4);
    float ss = v0.x*v0.x + v0.y*v0.y + v0.z*v0.z + v0.w*v0.w
             + v1.x*v1.x + v1.y*v1.y + v1.z*v1.z + v1.w*v1.w;
    #pragma unroll
    for (int off = 16; off > 0; off >>= 1) ss += __shfl_xor(ss, off, 64);  // 32-lane reduce
    float inv = 1.0f / fmaxf(sqrtf(ss), 1e-12f);
    uint4 o;
    o.x = f2bf(v0.x*inv) | ((unsigned)f2bf(v0.y*inv) << 16);
    o.y = f2bf(v0.z*inv) | ((unsigned)f2bf(v0.w*inv) << 16);
    o.z = f2bf(v1.x*inv) | ((unsigned)f2bf(v1.y*inv) << 16);
    o.w = f2bf(v1.z*inv) | ((unsigned)f2bf(v1.w*inv) << 16);
    *(uint4*)(Fs + ((size_t)c * N_TOTAL + row) * 8) = o;
}

__device__ __forceinline__ int tri_off(int x) { return x * NT - (x * (x - 1)) / 2; }

// Kernel 2: upper-triangular tiled F*F^T, fused exp epilogue, lock-free last-block finalize.
__global__ __launch_bounds__(256) void simloss_gemm(
    const unsigned short* __restrict__ Fs,
    float* __restrict__ S, int* __restrict__ counter,
    float* __restrict__ possum, float* __restrict__ out)
{
    // LDS: [chunk w][row], 16B units — matches gload16's uniform-base + lane*16
    __shared__ __hip_bfloat16 As[BM * BK];   // 8 KB
    __shared__ __hip_bfloat16 Bs[BN * BK];   // 8 KB
    __shared__ float fsum[4];
    __shared__ int   is_last;

    int b  = blockIdx.x;
    int bx = (int)(64.5f - sqrtf(64.5f * 64.5f - 2.0f * (float)b));
    if (bx < 0) bx = 0; if (bx > NT - 1) bx = NT - 1;
    while (bx > 0 && tri_off(bx) > b) --bx;
    while (bx < NT - 1 && tri_off(bx + 1) <= b) ++bx;
    const int by = bx + (b - tri_off(bx));
    const bool is_diag = (bx == by);

    const int i0 = bx * BM;
    const int j0 = by * BN;
    const int tid  = threadIdx.x;
    const int wave = tid >> 6;
    const int lane = tid & 63;
    const int wm = (wave & 1) * 64;
    const int wn = (wave >> 1) * 64;
    const int g  = lane >> 4;
    const int cj = lane & 15;

    f32x4 acc[4][4];
    #pragma unroll
    for (int a = 0; a < 4; ++a)
        #pragma unroll
        for (int c = 0; c < 4; ++c)
            acc[a][c] = (f32x4){0.f, 0.f, 0.f, 0.f};

    for (int kc = 0; kc < NCHUNK; kc += 4) {
        // wave w stages chunk kc+w for all 128 A-rows and 128 B-rows:
        // each gload16 reads 64 lanes x 16B fully contiguous (1 KB) [m97 pattern]
        const int ch = kc + wave;
        const unsigned short* bA = Fs + ((size_t)ch * N_TOTAL + i0) * 8;
        const unsigned short* bB = Fs + ((size_t)ch * N_TOTAL + j0) * 8;
        gload16(bA + (size_t)lane * 8,            &As[(wave * 128) * 8]);
        gload16(bA + (size_t)(64 + lane) * 8,     &As[(wave * 128 + 64) * 8]);
        gload16(bB + (size_t)lane * 8,            &Bs[(wave * 128) * 8]);
        gload16(bB + (size_t)(64 + lane) * 8,     &Bs[(wave * 128 + 64) * 8]);
        __syncthreads();

        bf16_8 a[4], bb[4];
        #pragma unroll
        for (int t = 0; t < 4; ++t) {
            a[t]  = *(const bf16_8*)(&As[(g * 128 + wm + t * 16 + cj) * 8]);
            bb[t] = *(const bf16_8*)(&Bs[(g * 128 + wn + t * 16 + cj) * 8]);
        }
        #pragma unroll
        for (int ti = 0; ti < 4; ++ti)
            #pragma unroll
            for (int tj = 0; tj < 4; ++tj)
                acc[ti][tj] = __builtin_amdgcn_mfma_f32_16x16x32_bf16(
                    a[ti], bb[tj], acc[ti][tj], 0, 0, 0);
        __syncthreads();
    }

    // ---- epilogue. C/D layout: col = lane&15, row = (lane>>4)*4 + reg [m89/m91]
    // positive-pair tiles (by==bx+32): accumulate sum of 2*INV_T*v over local diagonal
    if (by == bx + 32 && wm == wn) {
        float ds = 0.f;
        if ((cj >> 2) == g) {
            #pragma unroll
            for (int ti = 0; ti < 4; ++ti) ds += acc[ti][ti][cj & 3];
        }
        #pragma unroll
        for (int off = 1; off < 64; off <<= 1) ds += __shfl_xor(ds, off, 64);
        if (lane == 0) atomicAdd(possum, 2.0f * INV_T * ds);
    }
    // diag tiles: poison self-similarity so exp -> 0
    if (is_diag && wm == wn && (cj >> 2) == g) {
        #pragma unroll
        for (int ti = 0; ti < 4; ++ti) acc[ti][ti][cj & 3] = -1e30f;
    }

    float colsum[4] = {0.f, 0.f, 0.f, 0.f};
    #pragma unroll
    for (int ti = 0; ti < 4; ++ti) {
        #pragma unroll
        for (int r = 0; r < 4; ++r) {
            float es = 0.f;
            #pragma unroll
            for (int tj = 0; tj < 4; ++tj) {
                float e = __expf(acc[ti][tj][r] * INV_T);
                es += e;
                colsum[tj] += e;
            }
            #pragma unroll
            for (int off = 1; off < 16; off <<= 1)
                es += __shfl_xor(es, off, 64);
            if (cj == 0) atomicAdd(&S[i0 + wm + ti * 16 + g * 4 + r], es);
        }
    }
    if (!is_diag) {
        #pragma unroll
        for (int tj = 0; tj < 4; ++tj) {
            float cs = colsum[tj];
            cs += __shfl_xor(cs, 16, 64);
            cs += __shfl_xor(cs, 32, 64);
            if (g == 0) atomicAdd(&S[j0 + wn + tj * 16 + cj], cs);
        }
    }

    // ---- lock-free finalize: all cross-block data is device-scope atomics, so a
    // RELEASE counter add suffices (no per-block L2 invalidate — the round-3 bug).
    __syncthreads();   // all waves' S atomics drained (pre-barrier vmcnt(0))
    if (tid == 0)
        is_last = (__hip_atomic_fetch_add(counter, 1, __ATOMIC_RELEASE,
                                          __HIP_MEMORY_SCOPE_AGENT) == NBLOCKS - 1);
    __syncthreads();
    if (is_last) {
        __threadfence();   // single acquire, executed by exactly one block
        float a2 = 0.f;
        for (int i = tid; i < N_TOTAL; i += 256)
            a2 += __logf(__hip_atomic_load(&S[i], __ATOMIC_RELAXED,
                                           __HIP_MEMORY_SCOPE_AGENT));
        #pragma unroll
        for (int off = 32; off > 0; off >>= 1) a2 += __shfl_xor(a2, off, 64);
        if (lane == 0) fsum[wave] = a2;
        __syncthreads();
        if (tid == 0) {
            float ps = __hip_atomic_load(possum, __ATOMIC_RELAXED,
                                         __HIP_MEMORY_SCOPE_AGENT);
            out[0] = (fsum[0] + fsum[1] + fsum[2] + fsum[3] - ps) * (1.0f / N_TOTAL);
        }
    }
}

extern "C" void kernel_launch(void* const* d_in, const int* in_sizes, int n_in,
                              void* d_out, int out_size, void* d_ws, size_t ws_size,
                              hipStream_t stream) {
    const float* q = (const float*)d_in[0];
    const float* k = (const float*)d_in[1];
    float* out = (float*)d_out;

    char* ws = (char*)d_ws;
    const size_t f_bytes = (size_t)N_TOTAL * D_DIM * sizeof(unsigned short); // 4 MB
    unsigned short* Fs = (unsigned short*)ws;
    float* S      = (float*)(ws + f_bytes);
    int*   cnt    = (int*)(ws + f_bytes + N_TOTAL * sizeof(float));
    float* possum = (float*)(ws + f_bytes + N_TOTAL * sizeof(float) + 16);

    normalize_stage<<<N_TOTAL / 8, 256, 0, stream>>>(q, k, Fs, S, cnt, possum);
    simloss_gemm<<<NBLOCKS, 256, 0, stream>>>(Fs, S, cnt, possum, out);
}